// Round 5
// baseline (295.173 us; speedup 1.0000x reference)
//
#include <hip/hip_runtime.h>
#include <hip/hip_bf16.h>
#include <stdint.h>

#define N_TOT  8192
#define BHALF  4096
#define DDIM   128
#define NSPLIT 32

typedef short bf16x8 __attribute__((ext_vector_type(8)));
typedef float f32x4  __attribute__((ext_vector_type(4)));

__device__ __forceinline__ float ex2(float x) { return __builtin_amdgcn_exp2f(x); }

#define SCALE_C 3.798282440185f   /* sqrt(10*log2(e)): MFMA emits t = s*log2e */

__device__ __forceinline__ ushort2 cvt2(float a, float b) {
    __hip_bfloat162 h = __float22bfloat162_rn(make_float2(a, b));
    return *reinterpret_cast<ushort2*>(&h);
}

__device__ __forceinline__ bf16x8 cvt8(float4 lo, float4 hi) {
    union { bf16x8 v; ushort2 u[4]; } r;
    r.u[0] = cvt2(lo.x * SCALE_C, lo.y * SCALE_C);
    r.u[1] = cvt2(lo.z * SCALE_C, lo.w * SCALE_C);
    r.u[2] = cvt2(hi.x * SCALE_C, hi.y * SCALE_C);
    r.u[3] = cvt2(hi.z * SCALE_C, hi.w * SCALE_C);
    return r.v;
}

struct StageRegs { float4 v[4]; };

__device__ __forceinline__ StageRegs stage_load(const float* __restrict__ zi,
                                                const float* __restrict__ zj,
                                                int colBase, int ch, int tid) {
    StageRegs s;
    #pragma unroll
    for (int it = 0; it < 2; ++it) {
        int idx  = it * 512 + tid;
        int col  = idx >> 4, g = idx & 15;
        int gcol = colBase + ch * 64 + col;
        const float* cp = (gcol < BHALF) ? zi + gcol * DDIM
                                         : zj + (gcol - BHALF) * DDIM;
        s.v[it * 2]     = *reinterpret_cast<const float4*>(cp + g * 8);
        s.v[it * 2 + 1] = *reinterpret_cast<const float4*>(cp + g * 8 + 4);
    }
    return s;
}

__device__ __forceinline__ void stage_write(const StageRegs& s, int tid,
                                            unsigned short* buf) {
    #pragma unroll
    for (int it = 0; it < 2; ++it) {
        int idx  = it * 512 + tid;
        int col  = idx >> 4, g = idx & 15;
        int slot = g ^ (col & 7);                  // XOR bank swizzle
        *reinterpret_cast<bf16x8*>(&buf[col * 128 + slot * 8]) =
            cvt8(s.v[it * 2], s.v[it * 2 + 1]);
    }
}

// K1: streaming online-logsumexp over sim = (z z^T)/T rows, bf16 MFMA.
// Grid 1024 = 32 row-blocks x 32 col-splits (256 cols each): 4 blocks/CU,
// 32 waves/CU (8/SIMD) at VGPR<=64. Block: 8 waves of 32 rows. Inner: 2
// col-tiles batched per softmax rescale. Double-buffered LDS, 1 barrier/chunk.
// Also captures t_pos = sim[i, i^B]*log2e from the MFMA output (the pos
// column tile for a 16-row subtile is exactly tile rowTile^4096).
__launch_bounds__(512, 8)
__global__ void k_main(const float* __restrict__ zi, const float* __restrict__ zj,
                       float* __restrict__ pm, float* __restrict__ pl,
                       float* __restrict__ posb, float* __restrict__ out) {
    if (blockIdx.x == 0 && threadIdx.x == 0) out[0] = 0.f;  // init for k_finish atomics
    __shared__ unsigned short lds[2][64 * 128];   // 2 x 16 KB
    const int tid = threadIdx.x;
    const int w = tid >> 6, lane = tid & 63;
    const int q = lane >> 4, ln = lane & 15;
    const int rb = blockIdx.x >> 5, cs = blockIdx.x & 31;
    const int rowBase = rb * 256 + w * 32;
    const int colBase = cs * 256;

    // A fragments: 2 row-subtiles x 4 k-chunks, cast from fp32 (32 VGPR).
    bf16x8 afr[2][4];
    #pragma unroll
    for (int s = 0; s < 2; ++s) {
        int row = rowBase + s * 16 + ln;
        const float* rp = (row < BHALF) ? zi + row * DDIM
                                        : zj + (row - BHALF) * DDIM;
        #pragma unroll
        for (int kc = 0; kc < 4; ++kc) {
            float4 lo = *reinterpret_cast<const float4*>(rp + kc * 32 + q * 8);
            float4 hi = *reinterpret_cast<const float4*>(rp + kc * 32 + q * 8 + 4);
            afr[s][kc] = cvt8(lo, hi);
        }
    }

    float m[2][4], l[2][4];
    #pragma unroll
    for (int s = 0; s < 2; ++s)
        #pragma unroll
        for (int r = 0; r < 4; ++r) { m[s][r] = -1e38f; l[s][r] = 0.f; }

    StageRegs sr = stage_load(zi, zj, colBase, 0, tid);
    stage_write(sr, tid, lds[0]);
    __syncthreads();

    for (int ch = 0; ch < 4; ++ch) {
        const unsigned short* buf = lds[ch & 1];
        if (ch < 3) sr = stage_load(zi, zj, colBase, ch + 1, tid);  // prefetch

        #pragma unroll
        for (int ct2 = 0; ct2 < 2; ++ct2) {
            f32x4 acc[2][2];
            #pragma unroll
            for (int s = 0; s < 2; ++s)
                #pragma unroll
                for (int u = 0; u < 2; ++u) acc[s][u] = (f32x4){0.f, 0.f, 0.f, 0.f};

            #pragma unroll
            for (int u = 0; u < 2; ++u) {          // bfr transient: 16 VGPR
                int ct = ct2 * 2 + u;
                bf16x8 bfr[4];
                #pragma unroll
                for (int kc = 0; kc < 4; ++kc) {
                    int slot = (q + 4 * kc) ^ (ln & 7);
                    bfr[kc] = *reinterpret_cast<const bf16x8*>(
                        &buf[(ct * 16 + ln) * 128 + slot * 8]);
                }
                #pragma unroll
                for (int s = 0; s < 2; ++s)
                    #pragma unroll
                    for (int kc = 0; kc < 4; ++kc)
                        acc[s][u] = __builtin_amdgcn_mfma_f32_16x16x32_bf16(
                            afr[s][kc], bfr[kc], acc[s][u], 0, 0, 0);
            }

            const int c0 = colBase + ch * 64 + ct2 * 32;
            #pragma unroll
            for (int s = 0; s < 2; ++s) {
                const int rt = rowBase + s * 16;
                if (c0 == rt) {                      // diag in tile u=0
                    #pragma unroll
                    for (int r = 0; r < 4; ++r)
                        if (ln == q * 4 + r) acc[s][0][r] = -__builtin_inff();
                } else if (c0 + 16 == rt) {          // diag in tile u=1
                    #pragma unroll
                    for (int r = 0; r < 4; ++r)
                        if (ln == q * 4 + r) acc[s][1][r] = -__builtin_inff();
                }
                const int prt = rt ^ 4096;           // positive-pair col tile
                if (c0 == prt) {
                    #pragma unroll
                    for (int r = 0; r < 4; ++r)
                        if (ln == q * 4 + r) posb[rt + q * 4 + r] = acc[s][0][r];
                } else if (c0 + 16 == prt) {
                    #pragma unroll
                    for (int r = 0; r < 4; ++r)
                        if (ln == q * 4 + r) posb[rt + q * 4 + r] = acc[s][1][r];
                }
                #pragma unroll
                for (int r = 0; r < 4; ++r) {        // batched online update
                    float t0 = acc[s][0][r], t1 = acc[s][1][r];
                    float mo = m[s][r];
                    float mn = fmaxf(fmaxf(t0, t1), mo);
                    float sc = ex2(mo - mn);
                    float pv = ex2(t0 - mn) + ex2(t1 - mn);
                    l[s][r] = fmaf(l[s][r], sc, pv);
                    m[s][r] = mn;
                }
            }
        }

        if (ch < 3) stage_write(sr, tid, lds[(ch + 1) & 1]);
        __syncthreads();
    }

    // merge (m,l) across the 16 lanes (same quad) holding each row
    #pragma unroll
    for (int s = 0; s < 2; ++s) {
        #pragma unroll
        for (int r = 0; r < 4; ++r) {
            float mm = m[s][r], ll = l[s][r];
            #pragma unroll
            for (int msk = 1; msk < 16; msk <<= 1) {
                float om = __shfl_xor(mm, msk, 64);
                float ol = __shfl_xor(ll, msk, 64);
                float mn = fmaxf(mm, om);
                ll = ll * ex2(mm - mn) + ol * ex2(om - mn);
                mm = mn;
            }
            if (ln == 0) {
                int row = rowBase + s * 16 + q * 4 + r;
                pm[cs * N_TOT + row] = mm;
                pl[cs * N_TOT + row] = ll;
            }
        }
    }
}

// K2: per-row merge of 32 col-split partials. tp = t_pos (bits domain) from
// k_main. Extra exp(pos) term: pos appears in logits[:,0] AND inside neg.
// loss_i = ln2 * (M + log2(S) - tp); block-reduce, atomicAdd into out.
__global__ void k_finish(const float* __restrict__ pm, const float* __restrict__ pl,
                         const float* __restrict__ posb, float* __restrict__ out) {
    int row = blockIdx.x * 128 + threadIdx.x;
    float tp = posb[row];
    float mm[NSPLIT];
    float M = tp;
    #pragma unroll
    for (int j = 0; j < NSPLIT; ++j) {
        mm[j] = pm[j * N_TOT + row];
        M = fmaxf(M, mm[j]);
    }
    float S = ex2(tp - M);
    #pragma unroll
    for (int j = 0; j < NSPLIT; ++j)
        S += pl[j * N_TOT + row] * ex2(mm[j] - M);
    float li = 0.6931471805599453f * (M + __log2f(S) - tp);
    #pragma unroll
    for (int msk = 32; msk; msk >>= 1) li += __shfl_xor(li, msk, 64);
    __shared__ float red[2];
    if ((threadIdx.x & 63) == 0) red[threadIdx.x >> 6] = li;
    __syncthreads();
    if (threadIdx.x == 0)
        atomicAdd(out, (red[0] + red[1]) * (1.f / 8192.f));
}

extern "C" void kernel_launch(void* const* d_in, const int* in_sizes, int n_in,
                              void* d_out, int out_size, void* d_ws, size_t ws_size,
                              hipStream_t stream) {
    const float* zi = (const float*)d_in[0];
    const float* zj = (const float*)d_in[1];
    float* out = (float*)d_out;
    char* ws = (char*)d_ws;

    float* pm   = (float*)ws;                      // 32*8192*4 = 1 MB
    float* pl   = pm + NSPLIT * N_TOT;             // 1 MB
    float* posb = pl + NSPLIT * N_TOT;             // 32 KB

    hipLaunchKernelGGL(k_main,   dim3(1024), dim3(512), 0, stream, zi, zj, pm, pl, posb, out);
    hipLaunchKernelGGL(k_finish, dim3(64),   dim3(128), 0, stream, pm, pl, posb, out);
}

// Round 6
// 101.708 us; speedup vs baseline: 2.9021x; 2.9021x over previous
//
#include <hip/hip_runtime.h>
#include <hip/hip_bf16.h>
#include <stdint.h>

#define N_TOT  8192
#define BHALF  4096
#define DDIM   128
#define NSPLIT 32

typedef short bf16x8 __attribute__((ext_vector_type(8)));
typedef float f32x4  __attribute__((ext_vector_type(4)));

__device__ __forceinline__ float ex2(float x) { return __builtin_amdgcn_exp2f(x); }

#define SCALE_C 3.798282440185f   /* sqrt(10*log2(e)): MFMA emits t = s*log2e */

__device__ __forceinline__ ushort2 cvt2(float a, float b) {
    __hip_bfloat162 h = __float22bfloat162_rn(make_float2(a, b));
    return *reinterpret_cast<ushort2*>(&h);
}

__device__ __forceinline__ bf16x8 cvt8(float4 lo, float4 hi) {
    union { bf16x8 v; ushort2 u[4]; } r;
    r.u[0] = cvt2(lo.x * SCALE_C, lo.y * SCALE_C);
    r.u[1] = cvt2(lo.z * SCALE_C, lo.w * SCALE_C);
    r.u[2] = cvt2(hi.x * SCALE_C, hi.y * SCALE_C);
    r.u[3] = cvt2(hi.z * SCALE_C, hi.w * SCALE_C);
    return r.v;
}

struct StageRegs { float4 v[4]; };

__device__ __forceinline__ StageRegs stage_load(const float* __restrict__ zi,
                                                const float* __restrict__ zj,
                                                int colBase, int ch, int tid) {
    StageRegs s;
    #pragma unroll
    for (int it = 0; it < 2; ++it) {
        int idx  = it * 512 + tid;
        int col  = idx >> 4, g = idx & 15;
        int gcol = colBase + ch * 64 + col;
        const float* cp = (gcol < BHALF) ? zi + gcol * DDIM
                                         : zj + (gcol - BHALF) * DDIM;
        s.v[it * 2]     = *reinterpret_cast<const float4*>(cp + g * 8);
        s.v[it * 2 + 1] = *reinterpret_cast<const float4*>(cp + g * 8 + 4);
    }
    return s;
}

__device__ __forceinline__ void stage_write(const StageRegs& s, int tid,
                                            unsigned short* buf) {
    #pragma unroll
    for (int it = 0; it < 2; ++it) {
        int idx  = it * 512 + tid;
        int col  = idx >> 4, g = idx & 15;
        int slot = g ^ (col & 7);                  // XOR bank swizzle
        *reinterpret_cast<bf16x8*>(&buf[col * 128 + slot * 8]) =
            cvt8(s.v[it * 2], s.v[it * 2 + 1]);
    }
}

// K1: streaming online-logsumexp over sim = (z z^T)/T rows, bf16 MFMA.
// Grid 1024 = 32 row-blocks x 32 col-splits (256 cols each). Block: 8 waves
// of 32 rows. launch_bounds(512,4): compiler budget 128 VGPR -> allocates
// ~56; since 56<=64 the HW scheduler can still co-reside 4 blocks/CU
// (32 waves/CU, 128 KB LDS). DO NOT raise the waves arg to 8 - that
// collapses the allocator to 32 VGPR and spills ~900 MB/dispatch (round 5).
// Also captures t_pos = sim[i, i^B]*log2e from the MFMA output (the pos
// column tile for a 16-row subtile is exactly tile rowTile^4096).
__launch_bounds__(512, 4)
__global__ void k_main(const float* __restrict__ zi, const float* __restrict__ zj,
                       float* __restrict__ pm, float* __restrict__ pl,
                       float* __restrict__ posb, float* __restrict__ out) {
    if (blockIdx.x == 0 && threadIdx.x == 0) out[0] = 0.f;  // init for k_finish atomics
    __shared__ unsigned short lds[2][64 * 128];   // 2 x 16 KB
    const int tid = threadIdx.x;
    const int w = tid >> 6, lane = tid & 63;
    const int q = lane >> 4, ln = lane & 15;
    const int rb = blockIdx.x >> 5, cs = blockIdx.x & 31;
    const int rowBase = rb * 256 + w * 32;
    const int colBase = cs * 256;

    // A fragments: 2 row-subtiles x 4 k-chunks, cast from fp32 (32 VGPR).
    bf16x8 afr[2][4];
    #pragma unroll
    for (int s = 0; s < 2; ++s) {
        int row = rowBase + s * 16 + ln;
        const float* rp = (row < BHALF) ? zi + row * DDIM
                                        : zj + (row - BHALF) * DDIM;
        #pragma unroll
        for (int kc = 0; kc < 4; ++kc) {
            float4 lo = *reinterpret_cast<const float4*>(rp + kc * 32 + q * 8);
            float4 hi = *reinterpret_cast<const float4*>(rp + kc * 32 + q * 8 + 4);
            afr[s][kc] = cvt8(lo, hi);
        }
    }

    float m[2][4], l[2][4];
    #pragma unroll
    for (int s = 0; s < 2; ++s)
        #pragma unroll
        for (int r = 0; r < 4; ++r) { m[s][r] = -1e38f; l[s][r] = 0.f; }

    StageRegs sr = stage_load(zi, zj, colBase, 0, tid);
    stage_write(sr, tid, lds[0]);
    __syncthreads();

    for (int ch = 0; ch < 4; ++ch) {
        const unsigned short* buf = lds[ch & 1];
        if (ch < 3) sr = stage_load(zi, zj, colBase, ch + 1, tid);  // prefetch

        #pragma unroll
        for (int ct2 = 0; ct2 < 2; ++ct2) {
            f32x4 acc[2][2];
            #pragma unroll
            for (int s = 0; s < 2; ++s)
                #pragma unroll
                for (int u = 0; u < 2; ++u) acc[s][u] = (f32x4){0.f, 0.f, 0.f, 0.f};

            #pragma unroll
            for (int u = 0; u < 2; ++u) {          // bfr transient: 16 VGPR
                int ct = ct2 * 2 + u;
                bf16x8 bfr[4];
                #pragma unroll
                for (int kc = 0; kc < 4; ++kc) {
                    int slot = (q + 4 * kc) ^ (ln & 7);
                    bfr[kc] = *reinterpret_cast<const bf16x8*>(
                        &buf[(ct * 16 + ln) * 128 + slot * 8]);
                }
                #pragma unroll
                for (int s = 0; s < 2; ++s)
                    #pragma unroll
                    for (int kc = 0; kc < 4; ++kc)
                        acc[s][u] = __builtin_amdgcn_mfma_f32_16x16x32_bf16(
                            afr[s][kc], bfr[kc], acc[s][u], 0, 0, 0);
            }

            const int c0 = colBase + ch * 64 + ct2 * 32;
            #pragma unroll
            for (int s = 0; s < 2; ++s) {
                const int rt = rowBase + s * 16;
                if (c0 == rt) {                      // diag in tile u=0
                    #pragma unroll
                    for (int r = 0; r < 4; ++r)
                        if (ln == q * 4 + r) acc[s][0][r] = -__builtin_inff();
                } else if (c0 + 16 == rt) {          // diag in tile u=1
                    #pragma unroll
                    for (int r = 0; r < 4; ++r)
                        if (ln == q * 4 + r) acc[s][1][r] = -__builtin_inff();
                }
                const int prt = rt ^ 4096;           // positive-pair col tile
                if (c0 == prt) {
                    #pragma unroll
                    for (int r = 0; r < 4; ++r)
                        if (ln == q * 4 + r) posb[rt + q * 4 + r] = acc[s][0][r];
                } else if (c0 + 16 == prt) {
                    #pragma unroll
                    for (int r = 0; r < 4; ++r)
                        if (ln == q * 4 + r) posb[rt + q * 4 + r] = acc[s][1][r];
                }
                #pragma unroll
                for (int r = 0; r < 4; ++r) {        // batched online update
                    float t0 = acc[s][0][r], t1 = acc[s][1][r];
                    float mo = m[s][r];
                    float mn = fmaxf(fmaxf(t0, t1), mo);
                    float sc = ex2(mo - mn);
                    float pv = ex2(t0 - mn) + ex2(t1 - mn);
                    l[s][r] = fmaf(l[s][r], sc, pv);
                    m[s][r] = mn;
                }
            }
        }

        if (ch < 3) stage_write(sr, tid, lds[(ch + 1) & 1]);
        __syncthreads();
    }

    // merge (m,l) across the 16 lanes (same quad) holding each row
    #pragma unroll
    for (int s = 0; s < 2; ++s) {
        #pragma unroll
        for (int r = 0; r < 4; ++r) {
            float mm = m[s][r], ll = l[s][r];
            #pragma unroll
            for (int msk = 1; msk < 16; msk <<= 1) {
                float om = __shfl_xor(mm, msk, 64);
                float ol = __shfl_xor(ll, msk, 64);
                float mn = fmaxf(mm, om);
                ll = ll * ex2(mm - mn) + ol * ex2(om - mn);
                mm = mn;
            }
            if (ln == 0) {
                int row = rowBase + s * 16 + q * 4 + r;
                pm[cs * N_TOT + row] = mm;
                pl[cs * N_TOT + row] = ll;
            }
        }
    }
}

// K2: per-row merge of 32 col-split partials. tp = t_pos (bits domain) from
// k_main. Extra exp(pos) term: pos appears in logits[:,0] AND inside neg.
// loss_i = ln2 * (M + log2(S) - tp); block-reduce, atomicAdd into out.
__global__ void k_finish(const float* __restrict__ pm, const float* __restrict__ pl,
                         const float* __restrict__ posb, float* __restrict__ out) {
    int row = blockIdx.x * 128 + threadIdx.x;
    float tp = posb[row];
    float mm[NSPLIT];
    float M = tp;
    #pragma unroll
    for (int j = 0; j < NSPLIT; ++j) {
        mm[j] = pm[j * N_TOT + row];
        M = fmaxf(M, mm[j]);
    }
    float S = ex2(tp - M);
    #pragma unroll
    for (int j = 0; j < NSPLIT; ++j)
        S += pl[j * N_TOT + row] * ex2(mm[j] - M);
    float li = 0.6931471805599453f * (M + __log2f(S) - tp);
    #pragma unroll
    for (int msk = 32; msk; msk >>= 1) li += __shfl_xor(li, msk, 64);
    __shared__ float red[2];
    if ((threadIdx.x & 63) == 0) red[threadIdx.x >> 6] = li;
    __syncthreads();
    if (threadIdx.x == 0)
        atomicAdd(out, (red[0] + red[1]) * (1.f / 8192.f));
}

extern "C" void kernel_launch(void* const* d_in, const int* in_sizes, int n_in,
                              void* d_out, int out_size, void* d_ws, size_t ws_size,
                              hipStream_t stream) {
    const float* zi = (const float*)d_in[0];
    const float* zj = (const float*)d_in[1];
    float* out = (float*)d_out;
    char* ws = (char*)d_ws;

    float* pm   = (float*)ws;                      // 32*8192*4 = 1 MB
    float* pl   = pm + NSPLIT * N_TOT;             // 1 MB
    float* posb = pl + NSPLIT * N_TOT;             // 32 KB

    hipLaunchKernelGGL(k_main,   dim3(1024), dim3(512), 0, stream, zi, zj, pm, pl, posb, out);
    hipLaunchKernelGGL(k_finish, dim3(64),   dim3(128), 0, stream, pm, pl, posb, out);
}